// Round 8
// baseline (1152.755 us; speedup 1.0000x reference)
//
#include <hip/hip_runtime.h>

typedef unsigned short ushort_t;
typedef unsigned int   uint32;
typedef short s16x8 __attribute__((ext_vector_type(8)));
typedef float f32x4 __attribute__((ext_vector_type(4)));

#define HS    136    // h stride (272B rows: 16B aligned)
#define KOF   0      // kE [80][136] = 10880 elems (also FF fsl overlay: wid*2176)
#define VOF   10880  // vT [128][96] = 12288 elems
#define PWOF  23168  // per-wave [16][96] slices (P / q-bounce / O-bounce): 4*1536
#define BIGN  29312  // big = 58624 B; + h 21760 B = 80384 B LDS -> 2 blocks/CU
#define EPS_  1e-5f
#define SCALE2_ 0.25503483f   // log2(e)/sqrt(32): scores pre-scaled for exp2 softmax

#define MFMA16(a,b,c) __builtin_amdgcn_mfma_f32_16x16x32_bf16((a),(b),(c),0,0,0)

__device__ __forceinline__ float bfu(ushort_t u) {
  union { uint32 i; float f; } c; c.i = ((uint32)u) << 16; return c.f;
}
__device__ __forceinline__ void bf2(uint32 u, float& a, float& b) {
  union { uint32 i; float f; } c0, c1;
  c0.i = u << 16; c1.i = u & 0xffff0000u; a = c0.f; b = c1.f;
}
__device__ __forceinline__ ushort_t f2bf(float f) {
  union { float f; uint32 i; } c; c.f = f;
  uint32 r = c.i + 0x7fffu + ((c.i >> 16) & 1u);
  return (ushort_t)(r >> 16);
}

// Statistical dtype sniff on the first 256 ushorts of x (fp32 vs bf16 buffer).
__device__ bool sniff_f32(const ushort_t* x) {
  int insane = 0, zeros = 0;
  for (int i = 0; i < 256; ++i) {
    ushort_t u = x[i];
    int e = (u >> 7) & 0xFF;
    if (u == 0) zeros++;
    else if (e == 0xFF || e < 0x60) insane++;
  }
  return (insane >= 16) || (zeros >= 64);
}

struct WPack {
  const void* src[23];
  unsigned    off[23];
  unsigned    n[23];
};

__global__ __launch_bounds__(256) void canon(WPack p, const ushort_t* x, ushort_t* dst,
                                             int* flagOut) {
  const bool f32 = sniff_f32(x);
  const int gid = blockIdx.x * blockDim.x + threadIdx.x;
  const int gsz = gridDim.x * blockDim.x;
  for (int a = 0; a < 23; ++a) {
    unsigned n = p.n[a];
    ushort_t* d = dst + p.off[a];
    if (f32) {
      const float* s = (const float*)p.src[a];
      for (unsigned i = gid; i < n; i += gsz) d[i] = f2bf(s[i]);
    } else {
      const ushort_t* s = (const ushort_t*)p.src[a];
      for (unsigned i = gid; i < n; i += gsz) d[i] = s[i];
    }
  }
  if (blockIdx.x == 0 && threadIdx.x == 0) *flagOut = f32 ? 1 : 0;
}

__global__ __launch_bounds__(256, 2)   // 2 blocks/CU (LDS-capped) = 8 waves/CU
void vit_fused(const ushort_t* __restrict__ x,
               const ushort_t* __restrict__ patch_w,
               const ushort_t* __restrict__ patch_b,
               const ushort_t* __restrict__ cls_token,
               const ushort_t* __restrict__ pos_embed,
               const ushort_t* __restrict__ qkv_w,
               const ushort_t* __restrict__ qkv_b,
               const ushort_t* __restrict__ out_w,
               const ushort_t* __restrict__ out_b,
               const ushort_t* __restrict__ ln1_s,
               const ushort_t* __restrict__ ln1_b,
               const ushort_t* __restrict__ ln2_s,
               const ushort_t* __restrict__ ln2_b,
               const ushort_t* __restrict__ ff1_w,
               const ushort_t* __restrict__ ff1_b,
               const ushort_t* __restrict__ ff2_w,
               const ushort_t* __restrict__ ff2_b,
               const ushort_t* __restrict__ qr1_w,
               const ushort_t* __restrict__ qr1_b,
               const ushort_t* __restrict__ qr2_w,
               const ushort_t* __restrict__ qr2_b,
               const ushort_t* __restrict__ q_weights,
               const ushort_t* __restrict__ clf_w,
               const ushort_t* __restrict__ clf_b,
               const int* __restrict__ flag,
               void* __restrict__ out)
{
  __shared__ __align__(16) ushort_t h_s[80 * HS];   // 21760 B
  __shared__ __align__(16) ushort_t big[BIGN];      // 58624 B

  const int tid  = threadIdx.x;
  const int wid  = tid >> 6;
  const int lane = tid & 63;
  const int lr   = lane & 15;
  const int lq   = lane >> 4;
  const int b    = blockIdx.x;
  const bool f32m = (*flag != 0);

  // ---------------- stage x + patch_w into big ----------------
  uint32* bx = (uint32*)big;
  if (f32m) {
    const float* xf = (const float*)x + (size_t)b * 3072;
    for (int i = tid; i < 1536; i += 256) {
      uint32 lo = f2bf(xf[2 * i]);
      uint32 hi = f2bf(xf[2 * i + 1]);
      bx[i] = lo | (hi << 16);
    }
  } else {
    const uint32* xb = (const uint32*)x + (size_t)b * 1536;
    for (int i = tid; i < 1536; i += 256) bx[i] = xb[i];
  }
  {
    const uint32* pw = (const uint32*)patch_w;
    for (int i = tid; i < 3072; i += 256) bx[1536 + i] = pw[i];
  }
  __syncthreads();

  // ---------------- patch embed (scalar, ~1% of MACs) ----------------
  #pragma unroll 1
  for (int it = 0; it < 32; ++it) {
    int idx = tid + 256 * it;
    int p = idx >> 7, d = idx & 127;
    int pi = p >> 3, pj = p & 7;
    float acc = 0.f;
    #pragma unroll
    for (int c = 0; c < 3; ++c) {
      #pragma unroll
      for (int py = 0; py < 4; ++py) {
        const uint32* xr = bx + ((c * 1024 + (pi * 4 + py) * 32 + pj * 4) >> 1);
        const uint32* wr = bx + 1536 + ((d * 48 + c * 16 + py * 4) >> 1);
        #pragma unroll
        for (int q2 = 0; q2 < 2; ++q2) {
          float xa, xb2, wa, wb;
          bf2(xr[q2], xa, xb2); bf2(wr[q2], wa, wb);
          acc += xa * wa + xb2 * wb;
        }
      }
    }
    acc += bfu(patch_b[d]) + bfu(pos_embed[(1 + p) * 128 + d]);
    h_s[(1 + p) * HS + d] = f2bf(acc);
  }
  if (tid < 128) h_s[tid] = f2bf(bfu(cls_token[tid]) + bfu(pos_embed[tid]));
  for (int i = tid; i < 15 * HS; i += 256) h_s[65 * HS + i] = 0;   // zero pad rows 65..79

  // kv-unit ranges: compensate wave3's 2x attention / wave0's 2x FF
  const int st0 = (wid == 0) ? 0 : (wid == 1) ? 2 : (wid == 2) ? 35 : 68;
  const int st1 = (wid == 0) ? 2 : (wid == 1) ? 35 : (wid == 2) ? 68 : 80;

  // ---------------- transformer layers (3 barriers each) ----------------
  #pragma unroll 1
  for (int il = 0; il < 4; ++il) {
    __syncthreads();   // h stable; big free (prev FF fsl dead)

    // zero vT pad token-cols 80..95 (PV kc=2 reads tokens 64..95)
    for (int i = tid; i < 2048; i += 256)
      big[VOF + (i >> 4) * 96 + 80 + (i & 15)] = 0;

    const ushort_t* Wqkv = qkv_w + (size_t)il * 384 * 128;
    const ushort_t* Bqkv = qkv_b + il * 384;
    const ushort_t* Wo   = out_w + (size_t)il * 128 * 128;
    ushort_t* bw = big + PWOF + wid * 1536;   // private slice

    // ---- phase 1: k_all / vT_all (shared) + q for own m-tiles (registers)
    #pragma unroll 1
    for (int u = st0; u < st1; ++u) {
      int ty = u & 1, r = u >> 1;
      int mt = r >> 3, nt = r & 7;
      int m0 = mt * 16;
      int rb = (ty ? 256 : 128) + nt * 16;
      float bv = bfu(Bqkv[rb + lr]);
      f32x4 acc = {bv, bv, bv, bv};
      #pragma unroll
      for (int kc = 0; kc < 4; ++kc) {
        s16x8 a  = *(const s16x8*)&h_s[(m0 + lr) * HS + kc * 32 + lq * 8];
        s16x8 bb = *(const s16x8*)&Wqkv[(rb + lr) * 128 + kc * 32 + lq * 8];
        acc = MFMA16(a, bb, acc);
      }
      if (!ty) {   // k[token][dim], stride 136
        #pragma unroll
        for (int i = 0; i < 4; ++i)
          big[KOF + (m0 + lq * 4 + i) * 136 + nt * 16 + lr] = f2bf(acc[i]);
      } else {     // vT[dim][token], stride 96, pack 4 tokens
        uint32 w0 = (uint32)f2bf(acc[0]) | ((uint32)f2bf(acc[1]) << 16);
        uint32 w1 = (uint32)f2bf(acc[2]) | ((uint32)f2bf(acc[3]) << 16);
        uint32* dst = (uint32*)&big[VOF + (nt * 16 + lr) * 96 + m0 + lq * 4];
        dst[0] = w0; dst[1] = w1;
      }
    }

    // q fragments for own m-tiles -> REGISTERS, constant-indexed (no scratch)
    s16x8 qa0[4], qa1[4];
    auto compute_q = [&](int m0, s16x8 (&qa)[4]) {
      s16x8 ha[4];
      #pragma unroll
      for (int kc = 0; kc < 4; ++kc)
        ha[kc] = *(const s16x8*)&h_s[(m0 + lr) * HS + kc * 32 + lq * 8];
      #pragma unroll
      for (int ih = 0; ih < 4; ++ih) {           // FULL unroll: qa[ih] static
        int qoff = (ih & 1) * 768;               // double-buffered bounce
        #pragma unroll
        for (int n2 = 0; n2 < 2; ++n2) {
          int rb = ih * 32 + n2 * 16;            // q rows 0..127
          float bv = bfu(Bqkv[rb + lr]);
          f32x4 acc = {bv, bv, bv, bv};
          #pragma unroll
          for (int kc = 0; kc < 4; ++kc) {
            s16x8 bb = *(const s16x8*)&Wqkv[(rb + lr) * 128 + kc * 32 + lq * 8];
            acc = MFMA16(ha[kc], bb, acc);
          }
          #pragma unroll
          for (int i = 0; i < 4; ++i)
            bw[qoff + (lq * 4 + i) * 40 + n2 * 16 + lr] = f2bf(acc[i] * SCALE2_);
        }
        qa[ih] = *(const s16x8*)&bw[qoff + lr * 40 + lq * 8];
      }
    };
    compute_q(wid * 16, qa0);
    if (wid == 3) compute_q(64, qa1);
    __syncthreads();   // kE / vT ready

    // ---- phase 2: attention + out-proj + LN1, wave-private per own mt
    auto attn_one = [&](int m0, const s16x8 (&qa)[4]) {
      f32x4 opA[8];
      #pragma unroll
      for (int nt = 0; nt < 8; ++nt) {
        float bv = bfu(out_b[il * 128 + nt * 16 + lr]);
        opA[nt] = (f32x4){bv, bv, bv, bv};
      }
      #pragma unroll
      for (int ih = 0; ih < 4; ++ih) {           // FULL unroll: qa[ih] static
        s16x8 aq = qa[ih];
        f32x4 S[5];
        #pragma unroll
        for (int jt = 0; jt < 5; ++jt) {
          s16x8 bb = *(const s16x8*)&big[KOF + (jt * 16 + lr) * 136 + ih * 32 + lq * 8];
          f32x4 z = {0.f, 0.f, 0.f, 0.f};
          S[jt] = MFMA16(aq, bb, z);             // scores already *log2e/sqrt(dh)
        }
        float mx[4] = {-1e30f, -1e30f, -1e30f, -1e30f};
        #pragma unroll
        for (int jt = 0; jt < 5; ++jt)
          #pragma unroll
          for (int i = 0; i < 4; ++i) {
            float sv = S[jt][i];
            if (jt == 4 && lr > 0) sv = -1e30f;  // mask key tokens 65..79
            S[jt][i] = sv;
            mx[i] = fmaxf(mx[i], sv);
          }
        #pragma unroll
        for (int off = 1; off < 16; off <<= 1)
          #pragma unroll
          for (int i = 0; i < 4; ++i) mx[i] = fmaxf(mx[i], __shfl_xor(mx[i], off));
        float sm[4] = {0.f, 0.f, 0.f, 0.f};
        #pragma unroll
        for (int jt = 0; jt < 5; ++jt)
          #pragma unroll
          for (int i = 0; i < 4; ++i) {
            float pv = exp2f(S[jt][i] - mx[i]);  // exp2: scale folded into q
            S[jt][i] = pv; sm[i] += pv;
          }
        #pragma unroll
        for (int off = 1; off < 16; off <<= 1)
          #pragma unroll
          for (int i = 0; i < 4; ++i) sm[i] += __shfl_xor(sm[i], off);
        float inv[4];
        #pragma unroll
        for (int i = 0; i < 4; ++i) inv[i] = 1.f / sm[i];
        #pragma unroll
        for (int i = 0; i < 4; ++i) {
          #pragma unroll
          for (int jt = 0; jt < 5; ++jt)
            bw[(lq * 4 + i) * 96 + jt * 16 + lr] = f2bf(S[jt][i] * inv[i]);
          bw[(lq * 4 + i) * 96 + 80 + lr] = 0;   // exact-zero P cols 80..95
        }
        // PV
        f32x4 ov[2];
        #pragma unroll
        for (int n2 = 0; n2 < 2; ++n2) {
          f32x4 acc = {0.f, 0.f, 0.f, 0.f};
          #pragma unroll
          for (int kc = 0; kc < 3; ++kc) {
            s16x8 a  = *(const s16x8*)&bw[lr * 96 + kc * 32 + lq * 8];
            s16x8 bb = *(const s16x8*)&big[VOF + (ih * 32 + n2 * 16 + lr) * 96 + kc * 32 + lq * 8];
            acc = MFMA16(a, bb, acc);
          }
          ov[n2] = acc;
        }
        // O bounce (stride-40 overlay; same-wave in-order LDS) -> A-frag -> out-proj
        #pragma unroll
        for (int n2 = 0; n2 < 2; ++n2)
          #pragma unroll
          for (int i = 0; i < 4; ++i)
            bw[(lq * 4 + i) * 40 + n2 * 16 + lr] = f2bf(ov[n2][i]);
        s16x8 ao = *(const s16x8*)&bw[lr * 40 + lq * 8];
        #pragma unroll
        for (int nt = 0; nt < 8; ++nt) {
          s16x8 bb = *(const s16x8*)&Wo[(nt * 16 + lr) * 128 + ih * 32 + lq * 8];
          opA[nt] = MFMA16(ao, bb, opA[nt]);
        }
      } // heads

      // LN1 for this mt (wave-local)
      float sv[4] = {0, 0, 0, 0}, ssv[4] = {0, 0, 0, 0};
      #pragma unroll
      for (int nt = 0; nt < 8; ++nt)
        #pragma unroll
        for (int i = 0; i < 4; ++i) {
          float r = opA[nt][i] + bfu(h_s[(m0 + lq * 4 + i) * HS + nt * 16 + lr]);
          opA[nt][i] = r; sv[i] += r; ssv[i] += r * r;
        }
      #pragma unroll
      for (int off = 1; off < 16; off <<= 1)
        #pragma unroll
        for (int i = 0; i < 4; ++i) {
          sv[i]  += __shfl_xor(sv[i], off);
          ssv[i] += __shfl_xor(ssv[i], off);
        }
      float mean[4], inv2[4];
      #pragma unroll
      for (int i = 0; i < 4; ++i) {
        mean[i] = sv[i] * (1.f / 128.f);
        inv2[i] = rsqrtf(fmaxf(ssv[i] * (1.f / 128.f) - mean[i] * mean[i], 0.f) + EPS_);
      }
      #pragma unroll
      for (int nt = 0; nt < 8; ++nt) {
        float g  = bfu(ln1_s[il * 128 + nt * 16 + lr]);
        float be = bfu(ln1_b[il * 128 + nt * 16 + lr]);
        #pragma unroll
        for (int i = 0; i < 4; ++i)
          h_s[(m0 + lq * 4 + i) * HS + nt * 16 + lr] =
              f2bf((opA[nt][i] - mean[i]) * inv2[i] * g + be);
      }
    };
    attn_one(wid * 16, qa0);
    if (wid == 3) attn_one(64, qa1);
    __syncthreads();   // h(LN1) visible; kE dead -> fsl overlay

    // ---- phase 3: FF (ff1 relu -> ff2) + LN2; wave0 also does mt4
    {
      const ushort_t* W1 = ff1_w + (size_t)il * 256 * 128;
      const ushort_t* W2 = ff2_w + (size_t)il * 128 * 256;
      ushort_t* fsl = big + KOF + wid * 2176;   // [16][136] private (kE region)
      int nFF = (wid == 0) ? 2 : 1;
      #pragma unroll 1
      for (int s = 0; s < nFF; ++s) {
        int mt = (s == 0) ? wid : 4;
        int m0 = mt * 16;
        s16x8 ha[4];
        #pragma unroll
        for (int kc = 0; kc < 4; ++kc)
          ha[kc] = *(const s16x8*)&h_s[(m0 + lr) * HS + kc * 32 + lq * 8];
        f32x4 acc2[8];
        #pragma unroll
        for (int nt = 0; nt < 8; ++nt) {
          float bv = bfu(ff2_b[il * 128 + nt * 16 + lr]);
          acc2[nt] = (f32x4){bv, bv, bv, bv};
        }
        #pragma unroll
        for (int half = 0; half < 2; ++half) {
          #pragma unroll 1
          for (int n8 = 0; n8 < 8; ++n8) {
            int ng = half * 8 + n8;
            float bv = bfu(ff1_b[il * 256 + ng * 16 + lr]);
            f32x4 acc = {bv, bv, bv, bv};
            #pragma unroll
            for (int kc = 0; kc < 4; ++kc) {
              s16x8 bb = *(const s16x8*)&W1[(ng * 16 + lr) * 128 + kc * 32 + lq * 8];
              acc = MFMA16(ha[kc], bb, acc);
            }
            #pragma unroll
            for (int i = 0; i < 4; ++i)
              fsl[(lq * 4 + i) * 136 + n8 * 16 + lr] = f2bf(fmaxf(acc[i], 0.f));
          }
          #pragma unroll
          for (int kc = 0; kc < 4; ++kc) {
            s16x8 a2 = *(const s16x8*)&fsl[lr * 136 + kc * 32 + lq * 8];
            #pragma unroll
            for (int nt = 0; nt < 8; ++nt) {
              s16x8 bb = *(const s16x8*)&W2[(nt * 16 + lr) * 256 + half * 128 + kc * 32 + lq * 8];
              acc2[nt] = MFMA16(a2, bb, acc2[nt]);
            }
          }
        }
        // LN2 (wave-local)
        float sv[4] = {0, 0, 0, 0}, ssv[4] = {0, 0, 0, 0};
        #pragma unroll
        for (int nt = 0; nt < 8; ++nt)
          #pragma unroll
          for (int i = 0; i < 4; ++i) {
            float r = acc2[nt][i] + bfu(h_s[(m0 + lq * 4 + i) * HS + nt * 16 + lr]);
            acc2[nt][i] = r; sv[i] += r; ssv[i] += r * r;
          }
        #pragma unroll
        for (int off = 1; off < 16; off <<= 1)
          #pragma unroll
          for (int i = 0; i < 4; ++i) {
            sv[i]  += __shfl_xor(sv[i], off);
            ssv[i] += __shfl_xor(ssv[i], off);
          }
        float mean[4], inv2[4];
        #pragma unroll
        for (int i = 0; i < 4; ++i) {
          mean[i] = sv[i] * (1.f / 128.f);
          inv2[i] = rsqrtf(fmaxf(ssv[i] * (1.f / 128.f) - mean[i] * mean[i], 0.f) + EPS_);
        }
        #pragma unroll
        for (int nt = 0; nt < 8; ++nt) {
          float g  = bfu(ln2_s[il * 128 + nt * 16 + lr]);
          float be = bfu(ln2_b[il * 128 + nt * 16 + lr]);
          #pragma unroll
          for (int i = 0; i < 4; ++i)
            h_s[(m0 + lq * 4 + i) * HS + nt * 16 + lr] =
                f2bf((acc2[nt][i] - mean[i]) * inv2[i] * g + be);
        }
      }
    }
  } // layers

  // ---------------- head (tiny scalar) ----------------
  __syncthreads();
  float* scr = (float*)big;
  {
    int j = tid & 31;
    const uint32* hrow0 = (const uint32*)h_s;
    const uint32* w = (const uint32*)qr1_w + j * 64;
    float acc = 0.f;
    #pragma unroll 4
    for (int k2 = 0; k2 < 64; ++k2) {
      float ha, hb, wa, wb;
      bf2(hrow0[k2], ha, hb); bf2(w[k2], wa, wb);
      acc += ha * wa + hb * wb;
    }
    float u = fmaxf(acc + bfu(qr1_b[j]), 0.f);
    if (tid < 32) scr[tid] = u;
  }
  __syncthreads();
  if (tid < 10) {
    float qo[4]; float cp = 1.f;
    #pragma unroll
    for (int j2 = 0; j2 < 4; ++j2) {
      float acc = 0.f;
      #pragma unroll
      for (int k = 0; k < 32; ++k) acc += scr[k] * bfu(qr2_w[j2 * 32 + k]);
      float qin = tanhf(acc + bfu(qr2_b[j2]));
      cp *= cosf(qin) * cosf(bfu(q_weights[j2]));
      qo[j2] = cp;
    }
    const uint32* hrow0 = (const uint32*)h_s;
    const uint32* cw = (const uint32*)clf_w + tid * 66;   // clf row stride 132 elems
    float acc = 0.f;
    #pragma unroll 4
    for (int k2 = 0; k2 < 64; ++k2) {
      float ha, hb, wa, wb;
      bf2(hrow0[k2], ha, hb); bf2(cw[k2], wa, wb);
      acc += ha * wa + hb * wb;
    }
    #pragma unroll
    for (int d = 0; d < 4; ++d) acc += qo[d] * bfu(clf_w[tid * 132 + 128 + d]);
    acc += bfu(clf_b[tid]);
    if (f32m) ((float*)out)[b * 10 + tid] = acc;
    else      ((ushort_t*)out)[b * 10 + tid] = f2bf(acc);
  }
}

extern "C" void kernel_launch(void* const* d_in, const int* in_sizes, int n_in,
                              void* d_out, int out_size, void* d_ws, size_t ws_size,
                              hipStream_t stream) {
  WPack p;
  unsigned cur = 0;
  for (int i = 0; i < 23; ++i) {
    p.src[i] = d_in[i + 1];
    p.off[i] = cur;
    p.n[i]   = (unsigned)in_sizes[i + 1];
    cur += (p.n[i] + 7u) & ~7u;
  }
  ushort_t* wsb = (ushort_t*)d_ws;
  unsigned flag_off = (cur * 2 + 3u) & ~3u;          // byte offset, 4B aligned
  int* flagp = (int*)((char*)d_ws + flag_off);
  const ushort_t* x = (const ushort_t*)d_in[0];

  canon<<<dim3(128), dim3(256), 0, stream>>>(p, x, wsb, flagp);

  int B = out_size / 10;
  vit_fused<<<dim3(B), dim3(256), 0, stream>>>(
      x,
      wsb + p.off[0],  wsb + p.off[1],  wsb + p.off[2],  wsb + p.off[3],
      wsb + p.off[4],  wsb + p.off[5],  wsb + p.off[6],  wsb + p.off[7],
      wsb + p.off[8],  wsb + p.off[9],  wsb + p.off[10], wsb + p.off[11],
      wsb + p.off[12], wsb + p.off[13], wsb + p.off[14], wsb + p.off[15],
      wsb + p.off[16], wsb + p.off[17], wsb + p.off[18], wsb + p.off[19],
      wsb + p.off[20], wsb + p.off[21], wsb + p.off[22],
      flagp, d_out);
}

// Round 9
// 901.080 us; speedup vs baseline: 1.2793x; 1.2793x over previous
//
#include <hip/hip_runtime.h>

typedef unsigned short ushort_t;
typedef unsigned int   uint32;
typedef short s16x8 __attribute__((ext_vector_type(8)));
typedef float f32x4 __attribute__((ext_vector_type(4)));

#define HS    136    // h stride (272B rows: 16B aligned)
#define KOF   0      // kE [80][136] = 10880 elems (also FF fsl overlay: wid*2176)
#define VOF   10880  // vT [128][96] = 12288 elems
#define PWOF  23168  // per-wave [16][96] slices (q-bounce / P / O-bounce): 4*1536
#define BIGN  29312  // big = 58624 B; + h 21760 B = 80384 B LDS -> 2 blocks/CU
#define EPS_  1e-5f
#define SCALE2_ 0.25503483f   // log2(e)/sqrt(32): scores pre-scaled for exp2 softmax

#define MFMA16(a,b,c) __builtin_amdgcn_mfma_f32_16x16x32_bf16((a),(b),(c),0,0,0)

__device__ __forceinline__ float bfu(ushort_t u) {
  union { uint32 i; float f; } c; c.i = ((uint32)u) << 16; return c.f;
}
__device__ __forceinline__ void bf2(uint32 u, float& a, float& b) {
  union { uint32 i; float f; } c0, c1;
  c0.i = u << 16; c1.i = u & 0xffff0000u; a = c0.f; b = c1.f;
}
__device__ __forceinline__ ushort_t f2bf(float f) {
  union { float f; uint32 i; } c; c.f = f;
  uint32 r = c.i + 0x7fffu + ((c.i >> 16) & 1u);
  return (ushort_t)(r >> 16);
}

// Statistical dtype sniff on the first 256 ushorts of x (fp32 vs bf16 buffer).
__device__ bool sniff_f32(const ushort_t* x) {
  int insane = 0, zeros = 0;
  for (int i = 0; i < 256; ++i) {
    ushort_t u = x[i];
    int e = (u >> 7) & 0xFF;
    if (u == 0) zeros++;
    else if (e == 0xFF || e < 0x60) insane++;
  }
  return (insane >= 16) || (zeros >= 64);
}

struct WPack {
  const void* src[23];
  unsigned    off[23];
  unsigned    n[23];
};

__global__ __launch_bounds__(256) void canon(WPack p, const ushort_t* x, ushort_t* dst,
                                             int* flagOut) {
  const bool f32 = sniff_f32(x);
  const int gid = blockIdx.x * blockDim.x + threadIdx.x;
  const int gsz = gridDim.x * blockDim.x;
  for (int a = 0; a < 23; ++a) {
    unsigned n = p.n[a];
    ushort_t* d = dst + p.off[a];
    if (f32) {
      const float* s = (const float*)p.src[a];
      for (unsigned i = gid; i < n; i += gsz) d[i] = f2bf(s[i]);
    } else {
      const ushort_t* s = (const ushort_t*)p.src[a];
      for (unsigned i = gid; i < n; i += gsz) d[i] = s[i];
    }
  }
  if (blockIdx.x == 0 && threadIdx.x == 0) *flagOut = f32 ? 1 : 0;
}

__global__ __launch_bounds__(256, 2)   // 2 blocks/CU (LDS-capped) = 8 waves/CU
void vit_fused(const ushort_t* __restrict__ x,
               const ushort_t* __restrict__ patch_w,
               const ushort_t* __restrict__ patch_b,
               const ushort_t* __restrict__ cls_token,
               const ushort_t* __restrict__ pos_embed,
               const ushort_t* __restrict__ qkv_w,
               const ushort_t* __restrict__ qkv_b,
               const ushort_t* __restrict__ out_w,
               const ushort_t* __restrict__ out_b,
               const ushort_t* __restrict__ ln1_s,
               const ushort_t* __restrict__ ln1_b,
               const ushort_t* __restrict__ ln2_s,
               const ushort_t* __restrict__ ln2_b,
               const ushort_t* __restrict__ ff1_w,
               const ushort_t* __restrict__ ff1_b,
               const ushort_t* __restrict__ ff2_w,
               const ushort_t* __restrict__ ff2_b,
               const ushort_t* __restrict__ qr1_w,
               const ushort_t* __restrict__ qr1_b,
               const ushort_t* __restrict__ qr2_w,
               const ushort_t* __restrict__ qr2_b,
               const ushort_t* __restrict__ q_weights,
               const ushort_t* __restrict__ clf_w,
               const ushort_t* __restrict__ clf_b,
               const int* __restrict__ flag,
               void* __restrict__ out)
{
  __shared__ __align__(16) ushort_t h_s[80 * HS];   // 21760 B
  __shared__ __align__(16) ushort_t big[BIGN];      // 58624 B

  const int tid  = threadIdx.x;
  const int wid  = tid >> 6;
  const int lane = tid & 63;
  const int lr   = lane & 15;
  const int lq   = lane >> 4;
  const int b    = blockIdx.x;
  const bool f32m = (*flag != 0);

  // ---------------- stage x + patch_w into big ----------------
  uint32* bx = (uint32*)big;
  if (f32m) {
    const float* xf = (const float*)x + (size_t)b * 3072;
    for (int i = tid; i < 1536; i += 256) {
      uint32 lo = f2bf(xf[2 * i]);
      uint32 hi = f2bf(xf[2 * i + 1]);
      bx[i] = lo | (hi << 16);
    }
  } else {
    const uint32* xb = (const uint32*)x + (size_t)b * 1536;
    for (int i = tid; i < 1536; i += 256) bx[i] = xb[i];
  }
  {
    const uint32* pw = (const uint32*)patch_w;
    for (int i = tid; i < 3072; i += 256) bx[1536 + i] = pw[i];
  }
  __syncthreads();

  // ---------------- patch embed (scalar, ~1% of MACs) ----------------
  #pragma unroll 1
  for (int it = 0; it < 32; ++it) {
    int idx = tid + 256 * it;
    int p = idx >> 7, d = idx & 127;
    int pi = p >> 3, pj = p & 7;
    float acc = 0.f;
    #pragma unroll
    for (int c = 0; c < 3; ++c) {
      #pragma unroll
      for (int py = 0; py < 4; ++py) {
        const uint32* xr = bx + ((c * 1024 + (pi * 4 + py) * 32 + pj * 4) >> 1);
        const uint32* wr = bx + 1536 + ((d * 48 + c * 16 + py * 4) >> 1);
        #pragma unroll
        for (int q2 = 0; q2 < 2; ++q2) {
          float xa, xb2, wa, wb;
          bf2(xr[q2], xa, xb2); bf2(wr[q2], wa, wb);
          acc += xa * wa + xb2 * wb;
        }
      }
    }
    acc += bfu(patch_b[d]) + bfu(pos_embed[(1 + p) * 128 + d]);
    h_s[(1 + p) * HS + d] = f2bf(acc);
  }
  if (tid < 128) h_s[tid] = f2bf(bfu(cls_token[tid]) + bfu(pos_embed[tid]));
  for (int i = tid; i < 15 * HS; i += 256) h_s[65 * HS + i] = 0;   // zero pad rows 65..79

  // ---------------- transformer layers (3 barriers each) ----------------
  #pragma unroll 1
  for (int il = 0; il < 4; ++il) {
    __syncthreads();   // h stable; big free (prev FF fsl dead)

    // zero vT pad token-cols 80..95 (PV kc=2 reads tokens 64..95)
    for (int i = tid; i < 2048; i += 256)
      big[VOF + (i >> 4) * 96 + 80 + (i & 15)] = 0;

    const ushort_t* Wqkv = qkv_w + (size_t)il * 384 * 128;
    const ushort_t* Bqkv = qkv_b + il * 384;
    const ushort_t* Wo   = out_w + (size_t)il * 128 * 128;
    ushort_t* bw = big + PWOF + wid * 1536;   // private slice

    // ---- phase 1: k_all / vT_all only — balanced 20 units/wave
    //      (phases are barrier-bound: balance each phase independently)
    #pragma unroll 2
    for (int u = wid * 20; u < wid * 20 + 20; ++u) {
      int ty = u & 1, r = u >> 1;
      int mt = r >> 3, nt = r & 7;
      int m0 = mt * 16;
      int rb = (ty ? 256 : 128) + nt * 16;
      float bv = bfu(Bqkv[rb + lr]);
      f32x4 acc = {bv, bv, bv, bv};
      #pragma unroll
      for (int kc = 0; kc < 4; ++kc) {
        s16x8 a  = *(const s16x8*)&h_s[(m0 + lr) * HS + kc * 32 + lq * 8];
        s16x8 bb = *(const s16x8*)&Wqkv[(rb + lr) * 128 + kc * 32 + lq * 8];
        acc = MFMA16(a, bb, acc);
      }
      if (!ty) {   // k[token][dim], stride 136
        #pragma unroll
        for (int i = 0; i < 4; ++i)
          big[KOF + (m0 + lq * 4 + i) * 136 + nt * 16 + lr] = f2bf(acc[i]);
      } else {     // vT[dim][token], stride 96, pack 4 tokens
        uint32 w0 = (uint32)f2bf(acc[0]) | ((uint32)f2bf(acc[1]) << 16);
        uint32 w1 = (uint32)f2bf(acc[2]) | ((uint32)f2bf(acc[3]) << 16);
        uint32* dst = (uint32*)&big[VOF + (nt * 16 + lr) * 96 + m0 + lq * 4];
        dst[0] = w0; dst[1] = w1;
      }
    }
    __syncthreads();   // kE / vT ready

    // ---- phase 2: q (on the fly) + attention + out-proj + LN1, wave-private
    //      q reads only this wave's own h rows (untouched until own LN1) — safe
    auto attn_one = [&](int m0) {
      s16x8 ha[4];
      #pragma unroll
      for (int kc = 0; kc < 4; ++kc)
        ha[kc] = *(const s16x8*)&h_s[(m0 + lr) * HS + kc * 32 + lq * 8];
      f32x4 opA[8];
      #pragma unroll
      for (int nt = 0; nt < 8; ++nt) {
        float bv = bfu(out_b[il * 128 + nt * 16 + lr]);
        opA[nt] = (f32x4){bv, bv, bv, bv};
      }
      #pragma unroll 1   // one head live at a time: no register blow-up, no scratch
      for (int ih = 0; ih < 4; ++ih) {
        // q projection for this head (pre-scaled by log2e/sqrt(dh))
        #pragma unroll
        for (int n2 = 0; n2 < 2; ++n2) {
          int rb = ih * 32 + n2 * 16;
          float bv = bfu(Bqkv[rb + lr]);
          f32x4 acc = {bv, bv, bv, bv};
          #pragma unroll
          for (int kc = 0; kc < 4; ++kc) {
            s16x8 bb = *(const s16x8*)&Wqkv[(rb + lr) * 128 + kc * 32 + lq * 8];
            acc = MFMA16(ha[kc], bb, acc);
          }
          #pragma unroll
          for (int i = 0; i < 4; ++i)
            bw[(lq * 4 + i) * 40 + n2 * 16 + lr] = f2bf(acc[i] * SCALE2_);
        }
        s16x8 aq = *(const s16x8*)&bw[lr * 40 + lq * 8];
        // scores
        f32x4 S[5];
        #pragma unroll
        for (int jt = 0; jt < 5; ++jt) {
          s16x8 bb = *(const s16x8*)&big[KOF + (jt * 16 + lr) * 136 + ih * 32 + lq * 8];
          f32x4 z = {0.f, 0.f, 0.f, 0.f};
          S[jt] = MFMA16(aq, bb, z);
        }
        float mx[4] = {-1e30f, -1e30f, -1e30f, -1e30f};
        #pragma unroll
        for (int jt = 0; jt < 5; ++jt)
          #pragma unroll
          for (int i = 0; i < 4; ++i) {
            float sv = S[jt][i];
            if (jt == 4 && lr > 0) sv = -1e30f;  // mask key tokens 65..79
            S[jt][i] = sv;
            mx[i] = fmaxf(mx[i], sv);
          }
        #pragma unroll
        for (int off = 1; off < 16; off <<= 1)
          #pragma unroll
          for (int i = 0; i < 4; ++i) mx[i] = fmaxf(mx[i], __shfl_xor(mx[i], off));
        float sm[4] = {0.f, 0.f, 0.f, 0.f};
        #pragma unroll
        for (int jt = 0; jt < 5; ++jt)
          #pragma unroll
          for (int i = 0; i < 4; ++i) {
            float pv = exp2f(S[jt][i] - mx[i]);
            S[jt][i] = pv; sm[i] += pv;
          }
        #pragma unroll
        for (int off = 1; off < 16; off <<= 1)
          #pragma unroll
          for (int i = 0; i < 4; ++i) sm[i] += __shfl_xor(sm[i], off);
        float inv[4];
        #pragma unroll
        for (int i = 0; i < 4; ++i) inv[i] = 1.f / sm[i];
        #pragma unroll
        for (int i = 0; i < 4; ++i) {
          #pragma unroll
          for (int jt = 0; jt < 5; ++jt)
            bw[(lq * 4 + i) * 96 + jt * 16 + lr] = f2bf(S[jt][i] * inv[i]);
          bw[(lq * 4 + i) * 96 + 80 + lr] = 0;   // exact-zero P cols 80..95
        }
        // PV
        f32x4 ov[2];
        #pragma unroll
        for (int n2 = 0; n2 < 2; ++n2) {
          f32x4 acc = {0.f, 0.f, 0.f, 0.f};
          #pragma unroll
          for (int kc = 0; kc < 3; ++kc) {
            s16x8 a  = *(const s16x8*)&bw[lr * 96 + kc * 32 + lq * 8];
            s16x8 bb = *(const s16x8*)&big[VOF + (ih * 32 + n2 * 16 + lr) * 96 + kc * 32 + lq * 8];
            acc = MFMA16(a, bb, acc);
          }
          ov[n2] = acc;
        }
        // O bounce (stride-40 overlay; same-wave in-order LDS) -> A-frag -> out-proj
        #pragma unroll
        for (int n2 = 0; n2 < 2; ++n2)
          #pragma unroll
          for (int i = 0; i < 4; ++i)
            bw[(lq * 4 + i) * 40 + n2 * 16 + lr] = f2bf(ov[n2][i]);
        s16x8 ao = *(const s16x8*)&bw[lr * 40 + lq * 8];
        #pragma unroll
        for (int nt = 0; nt < 8; ++nt) {
          s16x8 bb = *(const s16x8*)&Wo[(nt * 16 + lr) * 128 + ih * 32 + lq * 8];
          opA[nt] = MFMA16(ao, bb, opA[nt]);
        }
      } // heads

      // LN1 for this mt (wave-local)
      float sv[4] = {0, 0, 0, 0}, ssv[4] = {0, 0, 0, 0};
      #pragma unroll
      for (int nt = 0; nt < 8; ++nt)
        #pragma unroll
        for (int i = 0; i < 4; ++i) {
          float r = opA[nt][i] + bfu(h_s[(m0 + lq * 4 + i) * HS + nt * 16 + lr]);
          opA[nt][i] = r; sv[i] += r; ssv[i] += r * r;
        }
      #pragma unroll
      for (int off = 1; off < 16; off <<= 1)
        #pragma unroll
        for (int i = 0; i < 4; ++i) {
          sv[i]  += __shfl_xor(sv[i], off);
          ssv[i] += __shfl_xor(ssv[i], off);
        }
      float mean[4], inv2[4];
      #pragma unroll
      for (int i = 0; i < 4; ++i) {
        mean[i] = sv[i] * (1.f / 128.f);
        inv2[i] = rsqrtf(fmaxf(ssv[i] * (1.f / 128.f) - mean[i] * mean[i], 0.f) + EPS_);
      }
      #pragma unroll
      for (int nt = 0; nt < 8; ++nt) {
        float g  = bfu(ln1_s[il * 128 + nt * 16 + lr]);
        float be = bfu(ln1_b[il * 128 + nt * 16 + lr]);
        #pragma unroll
        for (int i = 0; i < 4; ++i)
          h_s[(m0 + lq * 4 + i) * HS + nt * 16 + lr] =
              f2bf((opA[nt][i] - mean[i]) * inv2[i] * g + be);
      }
    };
    attn_one(wid * 16);
    if (wid == 3) attn_one(64);
    __syncthreads();   // h(LN1) visible; kE dead -> fsl overlay

    // ---- phase 3: FF (ff1 relu -> ff2) + LN2; wave0 also does mt4
    {
      const ushort_t* W1 = ff1_w + (size_t)il * 256 * 128;
      const ushort_t* W2 = ff2_w + (size_t)il * 128 * 256;
      ushort_t* fsl = big + KOF + wid * 2176;   // [16][136] private (kE region)
      int nFF = (wid == 0) ? 2 : 1;
      #pragma unroll 1
      for (int s = 0; s < nFF; ++s) {
        int mt = (s == 0) ? wid : 4;
        int m0 = mt * 16;
        s16x8 ha[4];
        #pragma unroll
        for (int kc = 0; kc < 4; ++kc)
          ha[kc] = *(const s16x8*)&h_s[(m0 + lr) * HS + kc * 32 + lq * 8];
        f32x4 acc2[8];
        #pragma unroll
        for (int nt = 0; nt < 8; ++nt) {
          float bv = bfu(ff2_b[il * 128 + nt * 16 + lr]);
          acc2[nt] = (f32x4){bv, bv, bv, bv};
        }
        #pragma unroll 1
        for (int half = 0; half < 2; ++half) {
          #pragma unroll 1
          for (int n8 = 0; n8 < 8; ++n8) {
            int ng = half * 8 + n8;
            float bv = bfu(ff1_b[il * 256 + ng * 16 + lr]);
            f32x4 acc = {bv, bv, bv, bv};
            #pragma unroll
            for (int kc = 0; kc < 4; ++kc) {
              s16x8 bb = *(const s16x8*)&W1[(ng * 16 + lr) * 128 + kc * 32 + lq * 8];
              acc = MFMA16(ha[kc], bb, acc);
            }
            #pragma unroll
            for (int i = 0; i < 4; ++i)
              fsl[(lq * 4 + i) * 136 + n8 * 16 + lr] = f2bf(fmaxf(acc[i], 0.f));
          }
          #pragma unroll
          for (int kc = 0; kc < 4; ++kc) {
            s16x8 a2 = *(const s16x8*)&fsl[lr * 136 + kc * 32 + lq * 8];
            #pragma unroll
            for (int nt = 0; nt < 8; ++nt) {
              s16x8 bb = *(const s16x8*)&W2[(nt * 16 + lr) * 256 + half * 128 + kc * 32 + lq * 8];
              acc2[nt] = MFMA16(a2, bb, acc2[nt]);
            }
          }
        }
        // LN2 (wave-local)
        float sv[4] = {0, 0, 0, 0}, ssv[4] = {0, 0, 0, 0};
        #pragma unroll
        for (int nt = 0; nt < 8; ++nt)
          #pragma unroll
          for (int i = 0; i < 4; ++i) {
            float r = acc2[nt][i] + bfu(h_s[(m0 + lq * 4 + i) * HS + nt * 16 + lr]);
            acc2[nt][i] = r; sv[i] += r; ssv[i] += r * r;
          }
        #pragma unroll
        for (int off = 1; off < 16; off <<= 1)
          #pragma unroll
          for (int i = 0; i < 4; ++i) {
            sv[i]  += __shfl_xor(sv[i], off);
            ssv[i] += __shfl_xor(ssv[i], off);
          }
        float mean[4], inv2[4];
        #pragma unroll
        for (int i = 0; i < 4; ++i) {
          mean[i] = sv[i] * (1.f / 128.f);
          inv2[i] = rsqrtf(fmaxf(ssv[i] * (1.f / 128.f) - mean[i] * mean[i], 0.f) + EPS_);
        }
        #pragma unroll
        for (int nt = 0; nt < 8; ++nt) {
          float g  = bfu(ln2_s[il * 128 + nt * 16 + lr]);
          float be = bfu(ln2_b[il * 128 + nt * 16 + lr]);
          #pragma unroll
          for (int i = 0; i < 4; ++i)
            h_s[(m0 + lq * 4 + i) * HS + nt * 16 + lr] =
                f2bf((acc2[nt][i] - mean[i]) * inv2[i] * g + be);
        }
      }
    }
  } // layers

  // ---------------- head (tiny scalar) ----------------
  __syncthreads();
  float* scr = (float*)big;
  {
    int j = tid & 31;
    const uint32* hrow0 = (const uint32*)h_s;
    const uint32* w = (const uint32*)qr1_w + j * 64;
    float acc = 0.f;
    #pragma unroll 4
    for (int k2 = 0; k2 < 64; ++k2) {
      float ha, hb, wa, wb;
      bf2(hrow0[k2], ha, hb); bf2(w[k2], wa, wb);
      acc += ha * wa + hb * wb;
    }
    float u = fmaxf(acc + bfu(qr1_b[j]), 0.f);
    if (tid < 32) scr[tid] = u;
  }
  __syncthreads();
  if (tid < 10) {
    float qo[4]; float cp = 1.f;
    #pragma unroll
    for (int j2 = 0; j2 < 4; ++j2) {
      float acc = 0.f;
      #pragma unroll
      for (int k = 0; k < 32; ++k) acc += scr[k] * bfu(qr2_w[j2 * 32 + k]);
      float qin = tanhf(acc + bfu(qr2_b[j2]));
      cp *= cosf(qin) * cosf(bfu(q_weights[j2]));
      qo[j2] = cp;
    }
    const uint32* hrow0 = (const uint32*)h_s;
    const uint32* cw = (const uint32*)clf_w + tid * 66;   // clf row stride 132 elems
    float acc = 0.f;
    #pragma unroll 4
    for (int k2 = 0; k2 < 64; ++k2) {
      float ha, hb, wa, wb;
      bf2(hrow0[k2], ha, hb); bf2(cw[k2], wa, wb);
      acc += ha * wa + hb * wb;
    }
    #pragma unroll
    for (int d = 0; d < 4; ++d) acc += qo[d] * bfu(clf_w[tid * 132 + 128 + d]);
    acc += bfu(clf_b[tid]);
    if (f32m) ((float*)out)[b * 10 + tid] = acc;
    else      ((ushort_t*)out)[b * 10 + tid] = f2bf(acc);
  }
}

extern "C" void kernel_launch(void* const* d_in, const int* in_sizes, int n_in,
                              void* d_out, int out_size, void* d_ws, size_t ws_size,
                              hipStream_t stream) {
  WPack p;
  unsigned cur = 0;
  for (int i = 0; i < 23; ++i) {
    p.src[i] = d_in[i + 1];
    p.off[i] = cur;
    p.n[i]   = (unsigned)in_sizes[i + 1];
    cur += (p.n[i] + 7u) & ~7u;
  }
  ushort_t* wsb = (ushort_t*)d_ws;
  unsigned flag_off = (cur * 2 + 3u) & ~3u;          // byte offset, 4B aligned
  int* flagp = (int*)((char*)d_ws + flag_off);
  const ushort_t* x = (const ushort_t*)d_in[0];

  canon<<<dim3(128), dim3(256), 0, stream>>>(p, x, wsb, flagp);

  int B = out_size / 10;
  vit_fused<<<dim3(B), dim3(256), 0, stream>>>(
      x,
      wsb + p.off[0],  wsb + p.off[1],  wsb + p.off[2],  wsb + p.off[3],
      wsb + p.off[4],  wsb + p.off[5],  wsb + p.off[6],  wsb + p.off[7],
      wsb + p.off[8],  wsb + p.off[9],  wsb + p.off[10], wsb + p.off[11],
      wsb + p.off[12], wsb + p.off[13], wsb + p.off[14], wsb + p.off[15],
      wsb + p.off[16], wsb + p.off[17], wsb + p.off[18], wsb + p.off[19],
      wsb + p.off[20], wsb + p.off[21], wsb + p.off[22],
      flagp, d_out);
}

// Round 10
// 874.515 us; speedup vs baseline: 1.3182x; 1.0304x over previous
//
#include <hip/hip_runtime.h>

typedef unsigned short ushort_t;
typedef unsigned int   uint32;
typedef short s16x8 __attribute__((ext_vector_type(8)));
typedef float f32x4 __attribute__((ext_vector_type(4)));

#define HS    136    // h stride (272B rows: 16B aligned, 4-bank rotation)
#define KOF   0      // kE [68][136] = 9248 elems (rows 68..79 of score-reads land in vT: masked)
#define VOF   9248   // vT [128][72] = 9216 elems (token cols 0..67 used; 64 via VALU fix)
#define SLOF  18464  // 5 per-wave slices of 2176 elems (q/P/O bounce + fsl)
#define BIGN  29344  // big = 58688 B; + h 21760 B = 80448 B -> 2 blocks/CU
#define EPS_  1e-5f
#define SCALE2_ 0.25503483f   // log2(e)/sqrt(32): scores pre-scaled for exp2 softmax

#define MFMA16(a,b,c) __builtin_amdgcn_mfma_f32_16x16x32_bf16((a),(b),(c),0,0,0)

__device__ __forceinline__ float bfu(ushort_t u) {
  union { uint32 i; float f; } c; c.i = ((uint32)u) << 16; return c.f;
}
__device__ __forceinline__ void bf2(uint32 u, float& a, float& b) {
  union { uint32 i; float f; } c0, c1;
  c0.i = u << 16; c1.i = u & 0xffff0000u; a = c0.f; b = c1.f;
}
__device__ __forceinline__ ushort_t f2bf(float f) {
  union { float f; uint32 i; } c; c.f = f;
  uint32 r = c.i + 0x7fffu + ((c.i >> 16) & 1u);
  return (ushort_t)(r >> 16);
}

// Statistical dtype sniff on the first 256 ushorts of x (fp32 vs bf16 buffer).
__device__ bool sniff_f32(const ushort_t* x) {
  int insane = 0, zeros = 0;
  for (int i = 0; i < 256; ++i) {
    ushort_t u = x[i];
    int e = (u >> 7) & 0xFF;
    if (u == 0) zeros++;
    else if (e == 0xFF || e < 0x60) insane++;
  }
  return (insane >= 16) || (zeros >= 64);
}

struct WPack {
  const void* src[23];
  unsigned    off[23];
  unsigned    n[23];
};

__global__ __launch_bounds__(256) void canon(WPack p, const ushort_t* x, ushort_t* dst,
                                             int* flagOut) {
  const bool f32 = sniff_f32(x);
  const int gid = blockIdx.x * blockDim.x + threadIdx.x;
  const int gsz = gridDim.x * blockDim.x;
  for (int a = 0; a < 23; ++a) {
    unsigned n = p.n[a];
    ushort_t* d = dst + p.off[a];
    if (f32) {
      const float* s = (const float*)p.src[a];
      for (unsigned i = gid; i < n; i += gsz) d[i] = f2bf(s[i]);
    } else {
      const ushort_t* s = (const ushort_t*)p.src[a];
      for (unsigned i = gid; i < n; i += gsz) d[i] = s[i];
    }
  }
  if (blockIdx.x == 0 && threadIdx.x == 0) *flagOut = f32 ? 1 : 0;
}

__global__ __launch_bounds__(320, 2)   // 5 waves/block, 2 blocks/CU (LDS 80448B)
void vit_fused(const ushort_t* __restrict__ x,
               const ushort_t* __restrict__ patch_w,
               const ushort_t* __restrict__ patch_b,
               const ushort_t* __restrict__ cls_token,
               const ushort_t* __restrict__ pos_embed,
               const ushort_t* __restrict__ qkv_w,
               const ushort_t* __restrict__ qkv_b,
               const ushort_t* __restrict__ out_w,
               const ushort_t* __restrict__ out_b,
               const ushort_t* __restrict__ ln1_s,
               const ushort_t* __restrict__ ln1_b,
               const ushort_t* __restrict__ ln2_s,
               const ushort_t* __restrict__ ln2_b,
               const ushort_t* __restrict__ ff1_w,
               const ushort_t* __restrict__ ff1_b,
               const ushort_t* __restrict__ ff2_w,
               const ushort_t* __restrict__ ff2_b,
               const ushort_t* __restrict__ qr1_w,
               const ushort_t* __restrict__ qr1_b,
               const ushort_t* __restrict__ qr2_w,
               const ushort_t* __restrict__ qr2_b,
               const ushort_t* __restrict__ q_weights,
               const ushort_t* __restrict__ clf_w,
               const ushort_t* __restrict__ clf_b,
               const int* __restrict__ flag,
               void* __restrict__ out)
{
  __shared__ __align__(16) ushort_t h_s[80 * HS];   // 21760 B
  __shared__ __align__(16) ushort_t big[BIGN];      // 58688 B

  const int tid  = threadIdx.x;
  const int wid  = tid >> 6;          // 0..4 == owned m-tile
  const int lane = tid & 63;
  const int lr   = lane & 15;
  const int lq   = lane >> 4;
  const int b    = blockIdx.x;
  const bool f32m = (*flag != 0);
  const int m0 = wid * 16;            // owned token rows

  // ---------------- stage x + patch_w into big ----------------
  uint32* bx = (uint32*)big;
  if (f32m) {
    const float* xf = (const float*)x + (size_t)b * 3072;
    for (int i = tid; i < 1536; i += 320) {
      uint32 lo = f2bf(xf[2 * i]);
      uint32 hi = f2bf(xf[2 * i + 1]);
      bx[i] = lo | (hi << 16);
    }
  } else {
    const uint32* xb = (const uint32*)x + (size_t)b * 1536;
    for (int i = tid; i < 1536; i += 320) bx[i] = xb[i];
  }
  {
    const uint32* pw = (const uint32*)patch_w;
    for (int i = tid; i < 3072; i += 320) bx[1536 + i] = pw[i];
  }
  __syncthreads();

  // ---------------- patch embed (scalar, ~1% of MACs) ----------------
  #pragma unroll 1
  for (int idx = tid; idx < 8192; idx += 320) {
    int p = idx >> 7, d = idx & 127;
    int pi = p >> 3, pj = p & 7;
    float acc = 0.f;
    #pragma unroll
    for (int c = 0; c < 3; ++c) {
      #pragma unroll
      for (int py = 0; py < 4; ++py) {
        const uint32* xr = bx + ((c * 1024 + (pi * 4 + py) * 32 + pj * 4) >> 1);
        const uint32* wr = bx + 1536 + ((d * 48 + c * 16 + py * 4) >> 1);
        #pragma unroll
        for (int q2 = 0; q2 < 2; ++q2) {
          float xa, xb2, wa, wb;
          bf2(xr[q2], xa, xb2); bf2(wr[q2], wa, wb);
          acc += xa * wa + xb2 * wb;
        }
      }
    }
    acc += bfu(patch_b[d]) + bfu(pos_embed[(1 + p) * 128 + d]);
    h_s[(1 + p) * HS + d] = f2bf(acc);
  }
  if (tid < 128) h_s[tid] = f2bf(bfu(cls_token[tid]) + bfu(pos_embed[tid]));
  for (int i = tid; i < 15 * HS; i += 320) h_s[65 * HS + i] = 0;   // zero pad rows 65..79

  // ---------------- transformer layers (2 barriers each) ----------------
  #pragma unroll 1
  for (int il = 0; il < 4; ++il) {
    __syncthreads();   // all prev-layer h writes visible; kE/vT free

    const ushort_t* Wqkv = qkv_w + (size_t)il * 384 * 128;
    const ushort_t* Bqkv = qkv_b + il * 384;
    const ushort_t* Wo   = out_w + (size_t)il * 128 * 128;
    ushort_t* bw = big + SLOF + wid * 2176;   // private slice

    // ---- phase 1: k_all / vT_all — 16 units/wave, perfectly balanced
    #pragma unroll 2
    for (int u = wid * 16; u < wid * 16 + 16; ++u) {
      int ty = u & 1, r = u >> 1;
      int mt = r >> 3, nt = r & 7;
      int km0 = mt * 16;
      int rb = (ty ? 256 : 128) + nt * 16;
      float bv = bfu(Bqkv[rb + lr]);
      f32x4 acc = {bv, bv, bv, bv};
      #pragma unroll
      for (int kc = 0; kc < 4; ++kc) {
        s16x8 a  = *(const s16x8*)&h_s[(km0 + lr) * HS + kc * 32 + lq * 8];
        s16x8 bb = *(const s16x8*)&Wqkv[(rb + lr) * 128 + kc * 32 + lq * 8];
        acc = MFMA16(a, bb, acc);
      }
      if (!ty) {   // k[token][dim], stride 136, rows < 68 only
        #pragma unroll
        for (int i = 0; i < 4; ++i) {
          int row = km0 + lq * 4 + i;
          if (row < 68) big[KOF + row * 136 + nt * 16 + lr] = f2bf(acc[i]);
        }
      } else {     // vT[dim][token], stride 72, tokens < 68 (col 64 = last real)
        int tk = km0 + lq * 4;
        if (tk < 68) {
          uint32 w0 = (uint32)f2bf(acc[0]) | ((uint32)f2bf(acc[1]) << 16);
          uint32 w1 = (uint32)f2bf(acc[2]) | ((uint32)f2bf(acc[3]) << 16);
          uint32* dst = (uint32*)&big[VOF + (nt * 16 + lr) * 72 + tk];
          dst[0] = w0; dst[1] = w1;
        }
      }
    }
    __syncthreads();   // kE / vT ready

    // ---- phase 2+3 fused, fully wave-private on own mt (no barriers) ----
    {
      // q A-frags from own (pre-LN1) h rows
      s16x8 ha[4];
      #pragma unroll
      for (int kc = 0; kc < 4; ++kc)
        ha[kc] = *(const s16x8*)&h_s[(m0 + lr) * HS + kc * 32 + lq * 8];
      f32x4 opA[8];
      #pragma unroll
      for (int nt = 0; nt < 8; ++nt) {
        float bv = bfu(out_b[il * 128 + nt * 16 + lr]);
        opA[nt] = (f32x4){bv, bv, bv, bv};
      }
      #pragma unroll 1   // one head live at a time
      for (int ih = 0; ih < 4; ++ih) {
        // q projection (pre-scaled by log2e/sqrt(dh))
        #pragma unroll
        for (int n2 = 0; n2 < 2; ++n2) {
          int rb = ih * 32 + n2 * 16;
          float bv = bfu(Bqkv[rb + lr]);
          f32x4 acc = {bv, bv, bv, bv};
          #pragma unroll
          for (int kc = 0; kc < 4; ++kc) {
            s16x8 bb = *(const s16x8*)&Wqkv[(rb + lr) * 128 + kc * 32 + lq * 8];
            acc = MFMA16(ha[kc], bb, acc);
          }
          #pragma unroll
          for (int i = 0; i < 4; ++i)
            bw[(lq * 4 + i) * 40 + n2 * 16 + lr] = f2bf(acc[i] * SCALE2_);
        }
        s16x8 aq = *(const s16x8*)&bw[lr * 40 + lq * 8];
        // scores (jt=4 rows 65..79 read garbage LDS: unconditionally masked below)
        f32x4 S[5];
        #pragma unroll
        for (int jt = 0; jt < 5; ++jt) {
          s16x8 bb = *(const s16x8*)&big[KOF + (jt * 16 + lr) * 136 + ih * 32 + lq * 8];
          f32x4 z = {0.f, 0.f, 0.f, 0.f};
          S[jt] = MFMA16(aq, bb, z);
        }
        float mx[4] = {-1e30f, -1e30f, -1e30f, -1e30f};
        #pragma unroll
        for (int jt = 0; jt < 5; ++jt)
          #pragma unroll
          for (int i = 0; i < 4; ++i) {
            float sv = S[jt][i];
            if (jt == 4 && lr > 0) sv = -1e30f;  // mask keys 65..79 (kills any NaN)
            S[jt][i] = sv;
            mx[i] = fmaxf(mx[i], sv);
          }
        #pragma unroll
        for (int off = 1; off < 16; off <<= 1)
          #pragma unroll
          for (int i = 0; i < 4; ++i) mx[i] = fmaxf(mx[i], __shfl_xor(mx[i], off));
        float sm[4] = {0.f, 0.f, 0.f, 0.f};
        #pragma unroll
        for (int jt = 0; jt < 5; ++jt)
          #pragma unroll
          for (int i = 0; i < 4; ++i) {
            float pv = exp2f(S[jt][i] - mx[i]);
            S[jt][i] = pv; sm[i] += pv;
          }
        #pragma unroll
        for (int off = 1; off < 16; off <<= 1)
          #pragma unroll
          for (int i = 0; i < 4; ++i) sm[i] += __shfl_xor(sm[i], off);
        float inv[4];
        #pragma unroll
        for (int i = 0; i < 4; ++i) inv[i] = 1.f / sm[i];
        // P (tokens 0..63 only) -> LDS, stride 72
        #pragma unroll
        for (int i = 0; i < 4; ++i)
          #pragma unroll
          for (int jt = 0; jt < 4; ++jt)
            bw[(lq * 4 + i) * 72 + jt * 16 + lr] = f2bf(S[jt][i] * inv[i]);
        // PV over tokens 0..63 (MFMA) + token 64 (VALU outer product)
        f32x4 ov[2];
        #pragma unroll
        for (int n2 = 0; n2 < 2; ++n2) {
          f32x4 acc = {0.f, 0.f, 0.f, 0.f};
          #pragma unroll
          for (int kc = 0; kc < 2; ++kc) {
            s16x8 a  = *(const s16x8*)&bw[lr * 72 + kc * 32 + lq * 8];
            s16x8 bb = *(const s16x8*)&big[VOF + (ih * 32 + n2 * 16 + lr) * 72 + kc * 32 + lq * 8];
            acc = MFMA16(a, bb, acc);
          }
          float v64 = bfu(big[VOF + (ih * 32 + n2 * 16 + lr) * 72 + 64]);
          #pragma unroll
          for (int i = 0; i < 4; ++i) {
            float p64 = __shfl(S[4][i], lane & 48) * inv[i];  // P[row][64] bcast from lr=0
            acc[i] += p64 * v64;
          }
          ov[n2] = acc;
        }
        // O bounce (stride-40 overlay; same-wave in-order LDS) -> A-frag -> out-proj
        #pragma unroll
        for (int n2 = 0; n2 < 2; ++n2)
          #pragma unroll
          for (int i = 0; i < 4; ++i)
            bw[(lq * 4 + i) * 40 + n2 * 16 + lr] = f2bf(ov[n2][i]);
        s16x8 ao = *(const s16x8*)&bw[lr * 40 + lq * 8];
        #pragma unroll
        for (int nt = 0; nt < 8; ++nt) {
          s16x8 bb = *(const s16x8*)&Wo[(nt * 16 + lr) * 128 + ih * 32 + lq * 8];
          opA[nt] = MFMA16(ao, bb, opA[nt]);
        }
      } // heads

      // LN1 (wave-local, own rows)
      float sv[4] = {0, 0, 0, 0}, ssv[4] = {0, 0, 0, 0};
      #pragma unroll
      for (int nt = 0; nt < 8; ++nt)
        #pragma unroll
        for (int i = 0; i < 4; ++i) {
          float r = opA[nt][i] + bfu(h_s[(m0 + lq * 4 + i) * HS + nt * 16 + lr]);
          opA[nt][i] = r; sv[i] += r; ssv[i] += r * r;
        }
      #pragma unroll
      for (int off = 1; off < 16; off <<= 1)
        #pragma unroll
        for (int i = 0; i < 4; ++i) {
          sv[i]  += __shfl_xor(sv[i], off);
          ssv[i] += __shfl_xor(ssv[i], off);
        }
      float mean[4], inv2[4];
      #pragma unroll
      for (int i = 0; i < 4; ++i) {
        mean[i] = sv[i] * (1.f / 128.f);
        inv2[i] = rsqrtf(fmaxf(ssv[i] * (1.f / 128.f) - mean[i] * mean[i], 0.f) + EPS_);
      }
      #pragma unroll
      for (int nt = 0; nt < 8; ++nt) {
        float g  = bfu(ln1_s[il * 128 + nt * 16 + lr]);
        float be = bfu(ln1_b[il * 128 + nt * 16 + lr]);
        #pragma unroll
        for (int i = 0; i < 4; ++i)
          h_s[(m0 + lq * 4 + i) * HS + nt * 16 + lr] =
              f2bf((opA[nt][i] - mean[i]) * inv2[i] * g + be);
      }

      // ---- FF immediately (own rows only; fsl = own slice, stride 136) ----
      const ushort_t* W1 = ff1_w + (size_t)il * 256 * 128;
      const ushort_t* W2 = ff2_w + (size_t)il * 128 * 256;
      s16x8 hf[4];
      #pragma unroll
      for (int kc = 0; kc < 4; ++kc)
        hf[kc] = *(const s16x8*)&h_s[(m0 + lr) * HS + kc * 32 + lq * 8];
      f32x4 acc2[8];
      #pragma unroll
      for (int nt = 0; nt < 8; ++nt) {
        float bv = bfu(ff2_b[il * 128 + nt * 16 + lr]);
        acc2[nt] = (f32x4){bv, bv, bv, bv};
      }
      #pragma unroll 1
      for (int half = 0; half < 2; ++half) {
        #pragma unroll 2
        for (int n8 = 0; n8 < 8; ++n8) {
          int ng = half * 8 + n8;
          float bv = bfu(ff1_b[il * 256 + ng * 16 + lr]);
          f32x4 acc = {bv, bv, bv, bv};
          #pragma unroll
          for (int kc = 0; kc < 4; ++kc) {
            s16x8 bb = *(const s16x8*)&W1[(ng * 16 + lr) * 128 + kc * 32 + lq * 8];
            acc = MFMA16(hf[kc], bb, acc);
          }
          #pragma unroll
          for (int i = 0; i < 4; ++i)
            bw[(lq * 4 + i) * 136 + n8 * 16 + lr] = f2bf(fmaxf(acc[i], 0.f));
        }
        #pragma unroll
        for (int kc = 0; kc < 4; ++kc) {
          s16x8 a2 = *(const s16x8*)&bw[lr * 136 + kc * 32 + lq * 8];
          #pragma unroll
          for (int nt = 0; nt < 8; ++nt) {
            s16x8 bb = *(const s16x8*)&W2[(nt * 16 + lr) * 256 + half * 128 + kc * 32 + lq * 8];
            acc2[nt] = MFMA16(a2, bb, acc2[nt]);
          }
        }
      }
      // LN2 (wave-local)
      float s2[4] = {0, 0, 0, 0}, ss2[4] = {0, 0, 0, 0};
      #pragma unroll
      for (int nt = 0; nt < 8; ++nt)
        #pragma unroll
        for (int i = 0; i < 4; ++i) {
          float r = acc2[nt][i] + bfu(h_s[(m0 + lq * 4 + i) * HS + nt * 16 + lr]);
          acc2[nt][i] = r; s2[i] += r; ss2[i] += r * r;
        }
      #pragma unroll
      for (int off = 1; off < 16; off <<= 1)
        #pragma unroll
        for (int i = 0; i < 4; ++i) {
          s2[i]  += __shfl_xor(s2[i], off);
          ss2[i] += __shfl_xor(ss2[i], off);
        }
      float mean2[4], invb[4];
      #pragma unroll
      for (int i = 0; i < 4; ++i) {
        mean2[i] = s2[i] * (1.f / 128.f);
        invb[i]  = rsqrtf(fmaxf(ss2[i] * (1.f / 128.f) - mean2[i] * mean2[i], 0.f) + EPS_);
      }
      #pragma unroll
      for (int nt = 0; nt < 8; ++nt) {
        float g  = bfu(ln2_s[il * 128 + nt * 16 + lr]);
        float be = bfu(ln2_b[il * 128 + nt * 16 + lr]);
        #pragma unroll
        for (int i = 0; i < 4; ++i)
          h_s[(m0 + lq * 4 + i) * HS + nt * 16 + lr] =
              f2bf((acc2[nt][i] - mean2[i]) * invb[i] * g + be);
      }
    }
  } // layers

  // ---------------- head (tiny scalar) ----------------
  __syncthreads();
  float* scr = (float*)big;
  {
    int j = tid & 31;
    const uint32* hrow0 = (const uint32*)h_s;
    const uint32* w = (const uint32*)qr1_w + j * 64;
    float acc = 0.f;
    #pragma unroll 4
    for (int k2 = 0; k2 < 64; ++k2) {
      float ha, hb, wa, wb;
      bf2(hrow0[k2], ha, hb); bf2(w[k2], wa, wb);
      acc += ha * wa + hb * wb;
    }
    float u = fmaxf(acc + bfu(qr1_b[j]), 0.f);
    if (tid < 32) scr[tid] = u;
  }
  __syncthreads();
  if (tid < 10) {
    float qo[4]; float cp = 1.f;
    #pragma unroll
    for (int j2 = 0; j2 < 4; ++j2) {
      float acc = 0.f;
      #pragma unroll
      for (int k = 0; k < 32; ++k) acc += scr[k] * bfu(qr2_w[j2 * 32 + k]);
      float qin = tanhf(acc + bfu(qr2_b[j2]));
      cp *= cosf(qin) * cosf(bfu(q_weights[j2]));
      qo[j2] = cp;
    }
    const uint32* hrow0 = (const uint32*)h_s;
    const uint32* cw = (const uint32*)clf_w + tid * 66;   // clf row stride 132 elems
    float acc = 0.f;
    #pragma unroll 4
    for (int k2 = 0; k2 < 64; ++k2) {
      float ha, hb, wa, wb;
      bf2(hrow0[k2], ha, hb); bf2(cw[k2], wa, wb);
      acc += ha * wa + hb * wb;
    }
    #pragma unroll
    for (int d = 0; d < 4; ++d) acc += qo[d] * bfu(clf_w[tid * 132 + 128 + d]);
    acc += bfu(clf_b[tid]);
    if (f32m) ((float*)out)[b * 10 + tid] = acc;
    else      ((ushort_t*)out)[b * 10 + tid] = f2bf(acc);
  }
}

extern "C" void kernel_launch(void* const* d_in, const int* in_sizes, int n_in,
                              void* d_out, int out_size, void* d_ws, size_t ws_size,
                              hipStream_t stream) {
  WPack p;
  unsigned cur = 0;
  for (int i = 0; i < 23; ++i) {
    p.src[i] = d_in[i + 1];
    p.off[i] = cur;
    p.n[i]   = (unsigned)in_sizes[i + 1];
    cur += (p.n[i] + 7u) & ~7u;
  }
  ushort_t* wsb = (ushort_t*)d_ws;
  unsigned flag_off = (cur * 2 + 3u) & ~3u;          // byte offset, 4B aligned
  int* flagp = (int*)((char*)d_ws + flag_off);
  const ushort_t* x = (const ushort_t*)d_in[0];

  canon<<<dim3(128), dim3(256), 0, stream>>>(p, x, wsb, flagp);

  int B = out_size / 10;
  vit_fused<<<dim3(B), dim3(320), 0, stream>>>(
      x,
      wsb + p.off[0],  wsb + p.off[1],  wsb + p.off[2],  wsb + p.off[3],
      wsb + p.off[4],  wsb + p.off[5],  wsb + p.off[6],  wsb + p.off[7],
      wsb + p.off[8],  wsb + p.off[9],  wsb + p.off[10], wsb + p.off[11],
      wsb + p.off[12], wsb + p.off[13], wsb + p.off[14], wsb + p.off[15],
      wsb + p.off[16], wsb + p.off[17], wsb + p.off[18], wsb + p.off[19],
      wsb + p.off[20], wsb + p.off[21], wsb + p.off[22],
      flagp, d_out);
}